// Round 6
// baseline (593.602 us; speedup 1.0000x reference)
//
#include <hip/hip_runtime.h>
#include <hip/hip_bf16.h>
#include <stdint.h>

typedef __bf16 bf16_t;
typedef __bf16 bf16x8 __attribute__((ext_vector_type(8)));
typedef float floatx4 __attribute__((ext_vector_type(4)));

#define MFMA_16x16x32_BF16(a, b, c) __builtin_amdgcn_mfma_f32_16x16x32_bf16((a), (b), (c), 0, 0, 0)

// load 8 contiguous elements as bf16x8 (fp32 source converts inline, RNE)
template <typename T>
__device__ __forceinline__ bf16x8 ld8_bf16(const T* p);

template <>
__device__ __forceinline__ bf16x8 ld8_bf16<bf16_t>(const bf16_t* p) {
  return *(const bf16x8*)p;
}
template <>
__device__ __forceinline__ bf16x8 ld8_bf16<float>(const float* p) {
  floatx4 f0 = *(const floatx4*)p;
  floatx4 f1 = *(const floatx4*)(p + 4);
  bf16x8 r;
#pragma unroll
  for (int j = 0; j < 4; j++) { r[j] = (bf16_t)f0[j]; r[j + 4] = (bf16_t)f1[j]; }
  return r;
}

// C[M,N] = A[M,K] @ B[N,K]^T (+ bias[N]); bf16 MFMA, fp32 accumulate, TOUT out.
// 128x128 tile, BK=32, 256 threads (2x2 waves of 64x64).
template <typename TA, typename TB, typename TOUT, bool BIAS>
__global__ __launch_bounds__(256)
void gemm_bt(const TA* __restrict__ A, const TB* __restrict__ B,
             const float* __restrict__ bias, TOUT* __restrict__ C,
             int M, int N, int K)
{
  __shared__ bf16_t As[128 * 32];   // row-major [128][32]
  __shared__ bf16_t Bs[128 * 32];
  const int t = threadIdx.x;
  const int lane = t & 63;
  const int wave = t >> 6;
  const int quad = lane >> 4, l15 = lane & 15;
  const int wr = wave >> 1, wc = wave & 1;
  const int m0 = blockIdx.y * 128, n0 = blockIdx.x * 128;

  // staging: 512 chunks of 8 elems per tile; thread t owns chunks t, t+256
  const int c0 = t, c1 = t + 256;
  const TA* ag0 = A + (size_t)(m0 + (c0 >> 2)) * K + (c0 & 3) * 8;
  const TA* ag1 = A + (size_t)(m0 + (c1 >> 2)) * K + (c1 & 3) * 8;
  const TB* bg0 = B + (size_t)(n0 + (c0 >> 2)) * K + (c0 & 3) * 8;
  const TB* bg1 = B + (size_t)(n0 + (c1 >> 2)) * K + (c1 & 3) * 8;

  floatx4 acc[4][4] = {};

  // prefetch tile 0 (converted to bf16 in registers)
  bf16x8 ar0 = ld8_bf16(ag0);
  bf16x8 ar1 = ld8_bf16(ag1);
  bf16x8 br0 = ld8_bf16(bg0);
  bf16x8 br1 = ld8_bf16(bg1);

  for (int k0 = 0; k0 < K; k0 += 32) {
    __syncthreads();
    *(bf16x8*)(As + c0 * 8) = ar0;
    *(bf16x8*)(As + c1 * 8) = ar1;
    *(bf16x8*)(Bs + c0 * 8) = br0;
    *(bf16x8*)(Bs + c1 * 8) = br1;
    __syncthreads();

    if (k0 + 32 < K) {   // prefetch next tile
      ar0 = ld8_bf16(ag0 + k0 + 32);
      ar1 = ld8_bf16(ag1 + k0 + 32);
      br0 = ld8_bf16(bg0 + k0 + 32);
      br1 = ld8_bf16(bg1 + k0 + 32);
    }

    bf16x8 af[4], bf[4];
#pragma unroll
    for (int i = 0; i < 4; i++)
      af[i] = *(const bf16x8*)(As + (wr * 64 + i * 16 + l15) * 32 + quad * 8);
#pragma unroll
    for (int i = 0; i < 4; i++)
      bf[i] = *(const bf16x8*)(Bs + (wc * 64 + i * 16 + l15) * 32 + quad * 8);
#pragma unroll
    for (int mi = 0; mi < 4; mi++)
#pragma unroll
      for (int ni = 0; ni < 4; ni++)
        acc[mi][ni] = MFMA_16x16x32_BF16(af[mi], bf[ni], acc[mi][ni]);
  }

  // epilogue: C/D layout col=lane&15, row=quad*4+reg
#pragma unroll
  for (int ni = 0; ni < 4; ni++) {
    const int col = n0 + wc * 64 + ni * 16 + l15;
    const float bv = BIAS ? bias[col] : 0.0f;
#pragma unroll
    for (int mi = 0; mi < 4; mi++) {
      const size_t rbase = (size_t)(m0 + wr * 64 + mi * 16 + quad * 4) * N + col;
#pragma unroll
      for (int r = 0; r < 4; r++)
        C[rbase + (size_t)r * N] = (TOUT)(acc[mi][ni][r] + bv);
    }
  }
}

// Flash-style blocked attention on a chunk of `rows` rows (multiple of 512).
// qkv: [rows][3072] bf16 chunk-local (cols t*1024 + h*64 + d) -> out [rows][1024].
// grid.x = 16 * (rows/256): h = idx&15, qtile = idx>>4; 4 waves x 64 q-rows.
__global__ __launch_bounds__(256)
void attn_kernel(const bf16_t* __restrict__ qkv, bf16_t* __restrict__ out)
{
  constexpr int VS = 72;  // padded LDS row stride (144 B)
  __shared__ bf16_t Ks[64 * VS];      // K tile [key][d]
  __shared__ bf16_t Vt[64 * VS];      // V tile transposed [d][key]
  __shared__ bf16_t Ps[4][64 * VS];   // per-wave P [qrow][key]

  const int h     = blockIdx.x & 15;
  const int qtile = blockIdx.x >> 4;

  const int t = threadIdx.x;
  const int wave = t >> 6, lane = t & 63;
  const int quad = lane >> 4, l15 = lane & 15;

  const int qrow0 = qtile * 256 + wave * 64;
  const int krow0 = (qtile >> 1) * 512;   // group base (2 qtiles per group)
  const int qcol = h * 64;
  const int kcol = 1024 + h * 64;
  const int vcol = 2048 + h * 64;

  // Q fragments (A-operand: A[m=lane&15][k=quad*8+j])
  bf16x8 qf[4][2];
#pragma unroll
  for (int mi = 0; mi < 4; mi++)
#pragma unroll
    for (int kb = 0; kb < 2; kb++)
      qf[mi][kb] = *(const bf16x8*)(qkv + (size_t)(qrow0 + mi * 16 + l15) * 3072 + qcol + kb * 32 + quad * 8);

  floatx4 o[4][4] = {};
  float mrow[4][4], lrow[4][4];
#pragma unroll
  for (int mi = 0; mi < 4; mi++)
#pragma unroll
    for (int r = 0; r < 4; r++) { mrow[mi][r] = -1e30f; lrow[mi][r] = 0.0f; }

  for (int it = 0; it < 8; it++) {
    __syncthreads();
    // stage K tile [64 keys][64 d]
    {
      int c = t;
#pragma unroll
      for (int rr = 0; rr < 2; rr++, c += 256) {
        const int key = c >> 3, dc = c & 7;
        bf16x8 kv = *(const bf16x8*)(qkv + (size_t)(krow0 + it * 64 + key) * 3072 + kcol + dc * 8);
        *(bf16x8*)(Ks + key * VS + dc * 8) = kv;
      }
      // stage V transposed: Vt[d][key]
      c = t;
#pragma unroll
      for (int rr = 0; rr < 2; rr++, c += 256) {
        const int key = c & 63, dg = c >> 6;
        bf16x8 vv = *(const bf16x8*)(qkv + (size_t)(krow0 + it * 64 + key) * 3072 + vcol + dg * 8);
#pragma unroll
        for (int j = 0; j < 8; j++)
          Vt[(dg * 8 + j) * VS + key] = vv[j];
      }
    }
    __syncthreads();

    // K fragments (B-operand B[n=key][k=d])
    bf16x8 kf[4][2];
#pragma unroll
    for (int ni = 0; ni < 4; ni++)
#pragma unroll
      for (int kb = 0; kb < 2; kb++)
        kf[ni][kb] = *(const bf16x8*)(Ks + (ni * 16 + l15) * VS + kb * 32 + quad * 8);

    // S = Q K^T per mi-block, then online softmax
#pragma unroll
    for (int mi = 0; mi < 4; mi++) {
      floatx4 s[4] = {};
#pragma unroll
      for (int ni = 0; ni < 4; ni++) {
        s[ni] = MFMA_16x16x32_BF16(qf[mi][0], kf[ni][0], s[ni]);
        s[ni] = MFMA_16x16x32_BF16(qf[mi][1], kf[ni][1], s[ni]);
      }
#pragma unroll
      for (int r = 0; r < 4; r++) {       // row = mi*16 + quad*4 + r
        float mx = -1e30f;
#pragma unroll
        for (int ni = 0; ni < 4; ni++) {
          s[ni][r] *= 0.125f;             // dh^-0.5
          mx = fmaxf(mx, s[ni][r]);
        }
#pragma unroll
        for (int off = 1; off < 16; off <<= 1)
          mx = fmaxf(mx, __shfl_xor(mx, off, 64));   // reduce over 16-lane group
        const float mnew = fmaxf(mrow[mi][r], mx);
        const float alpha = __expf(mrow[mi][r] - mnew);
        mrow[mi][r] = mnew;
        float psum = 0.0f;
#pragma unroll
        for (int ni = 0; ni < 4; ni++) {
          const float p = __expf(s[ni][r] - mnew);
          psum += p;
          Ps[wave][(mi * 16 + quad * 4 + r) * VS + ni * 16 + l15] = (bf16_t)p;
          o[mi][ni][r] *= alpha;
        }
#pragma unroll
        for (int off = 1; off < 16; off <<= 1)
          psum += __shfl_xor(psum, off, 64);
        lrow[mi][r] = lrow[mi][r] * alpha + psum;
      }
    }
    __syncthreads();   // P writes drained; Vt stable

    // O += P @ V : P as A-operand from LDS, V^T as B-operand (Vt[d][key])
    bf16x8 vf[4][2];
#pragma unroll
    for (int ni = 0; ni < 4; ni++)
#pragma unroll
      for (int kb = 0; kb < 2; kb++)
        vf[ni][kb] = *(const bf16x8*)(Vt + (ni * 16 + l15) * VS + kb * 32 + quad * 8);
#pragma unroll
    for (int mi = 0; mi < 4; mi++) {
      bf16x8 pf0 = *(const bf16x8*)(Ps[wave] + (mi * 16 + l15) * VS + quad * 8);
      bf16x8 pf1 = *(const bf16x8*)(Ps[wave] + (mi * 16 + l15) * VS + 32 + quad * 8);
#pragma unroll
      for (int ni = 0; ni < 4; ni++) {
        o[mi][ni] = MFMA_16x16x32_BF16(pf0, vf[ni][0], o[mi][ni]);
        o[mi][ni] = MFMA_16x16x32_BF16(pf1, vf[ni][1], o[mi][ni]);
      }
    }
  }

  // normalize and write: out[row][h*64 + d] (chunk-local)
#pragma unroll
  for (int mi = 0; mi < 4; mi++)
#pragma unroll
    for (int r = 0; r < 4; r++) {
      const float inv = 1.0f / lrow[mi][r];
      const size_t rbase = (size_t)(qrow0 + mi * 16 + quad * 4 + r) * 1024 + h * 64 + l15;
#pragma unroll
      for (int ni = 0; ni < 4; ni++)
        out[rbase + ni * 16] = (bf16_t)(o[mi][ni][r] * inv);
    }
}

extern "C" void kernel_launch(void* const* d_in, const int* in_sizes, int n_in,
                              void* d_out, int out_size, void* d_ws, size_t ws_size,
                              hipStream_t stream)
{
  // Inputs fp32 (reference setup_inputs); OUTPUT fp32 (reference returns fp32).
  const float* x     = (const float*)d_in[0];   // [4,4096,1024]
  const float* w_qkv = (const float*)d_in[1];   // [3072,1024]
  const float* w_out = (const float*)d_in[2];   // [1024,1024]
  const float* b_out = (const float*)d_in[3];   // [1024]
  float* out = (float*)d_out;                   // [4,4096,1024] fp32

  // bf16 intermediates in ws: 8192 B per row (qkv 6144 + att 2048).
  // Adaptive chunking: largest power-of-two row count that fits ws.
  int rows = 16384;
  while ((size_t)rows * 8192 > ws_size && rows > 512) rows >>= 1;
  const int nchunk = 16384 / rows;

  bf16_t* qkv_c = (bf16_t*)d_ws;                    // [rows][3072]
  bf16_t* att_c = qkv_c + (size_t)rows * 3072;      // [rows][1024]

  for (int c = 0; c < nchunk; c++) {
    const float* xc = x + (size_t)c * rows * 1024;
    float* outc = out + (size_t)c * rows * 1024;
    // 1) QKV projection (fp32 in -> bf16 qkv)
    gemm_bt<float, float, bf16_t, false><<<dim3(3072 / 128, rows / 128), 256, 0, stream>>>(
        xc, w_qkv, nullptr, qkv_c, rows, 3072, 1024);
    // 2) blocked attention
    attn_kernel<<<dim3(16 * (rows / 256)), 256, 0, stream>>>(qkv_c, att_c);
    // 3) output projection + bias (bf16 x fp32 -> fp32 out)
    gemm_bt<bf16_t, float, float, true><<<dim3(1024 / 128, rows / 128), 256, 0, stream>>>(
        att_c, w_out, b_out, outc, rows, 1024, 1024);
  }
}